// Round 14
// baseline (523.339 us; speedup 1.0000x reference)
//
#include <hip/hip_runtime.h>
#include <hip/hip_bf16.h>

typedef __attribute__((ext_vector_type(8))) short bf16x8;
typedef __attribute__((ext_vector_type(4))) float f32x4;

__device__ __forceinline__ unsigned short f2bf(float f) {
  __hip_bfloat16 h = __float2bfloat16(f);
  return *reinterpret_cast<unsigned short*>(&h);
}

__device__ __forceinline__ void gld_lds16(void* lds, const void* g) {
  __builtin_amdgcn_global_load_lds(
      (const __attribute__((address_space(1))) unsigned int*)g,
      (__attribute__((address_space(3))) unsigned int*)lds, 16, 0, 0);
}

// ---------------------------------------------------------------------------
// Kernel 1 v6: offset conv (fp64) + gather + cast. 8-ROW blocks, 256 blocks
// x 512 threads (8 waves/CU, same wave count as v5's 2x256). k1 is HBM-bound
// (v5: 1.2 GB -> 192 us floor, measured 205): cut conv staging 805 -> 335 MB
// by computing 8 output rows from 10 staged input rows (re-read 3x -> 1.25x).
// Chunk = 8 ch; tile[10][128][12] (48B stride: b128 window (3px+q) mod 8,
// 3 coprime 8 -> same near-free conflict profile v5 measured). Weights stay
// in LDS (wlf) per the v3/v4 s_load/lgkmcnt lesson. fp64 product set
// identical; accumulation regrouped (2 quad chains) ~1e-13, proven safe.
// ---------------------------------------------------------------------------
__global__ __launch_bounds__(512) void k1_offs_gather(
    const float* __restrict__ in, const float* __restrict__ w_off,
    const float* __restrict__ b_off, unsigned short* __restrict__ samp) {
  __shared__ float tile[10][128][12];  // 61.4 KB; 48B row stride
  __shared__ float wlf[144];           // [tap][c(8)][o(2)] current chunk
  __shared__ int lin_lds[1024];

  const int bid = blockIdx.x;          // 0..255
  const int b = bid >> 4, h0 = (bid & 15) << 3;
  const int t = threadIdx.x;
  const int px_ = t & 127;
  const int rb = t >> 7;               // 0..3; thread owns rows rb, rb+4

  double acY[2][2] = {{0, 0}, {0, 0}};
  double acX[2][2] = {{0, 0}, {0, 0}};

  for (int chunk = 0; chunk < 32; ++chunk) {
    const int c0 = chunk * 8;
    __syncthreads();  // protect tile/wlf from previous chunk's readers
    // weights slice: [tap][c(8)][o(2)], 144 floats
    if (t < 144) {
      const int tap = t >> 4, r = t & 15;
      wlf[t] = w_off[tap * 512 + (c0 + (r >> 1)) * 2 + (r & 1)];
    }
    // stage rows h0-1 .. h0+8, 128 px, 8 ch (2560 float4 = 5/thread)
    #pragma unroll
    for (int it = 0; it < 5; ++it) {
      const int idx = it * 512 + t;          // 0..2559
      const int row = idx >> 8;              // 0..9
      const int px = (idx & 255) >> 1, q = idx & 1;
      const int hh = h0 - 1 + row;
      float4 v = make_float4(0.f, 0.f, 0.f, 0.f);
      if ((unsigned)hh < 128u)
        v = *(const float4*)(in + ((size_t)(b * 128 + hh) * 128 + px) * 256 +
                             c0 + q * 4);
      *(float4*)&tile[row][px][q * 4] = v;
    }
    __syncthreads();
    // 9 taps x 2 quads x 2 pixels; tile b128, weights LDS broadcast
    #pragma unroll
    for (int tap = 0; tap < 9; ++tap) {
      const int dr = tap / 3, dc = tap % 3 - 1;
      const int wsrc = px_ + dc;
      if ((unsigned)wsrc >= 128u) continue;
      const float* wf = &wlf[tap * 16];
      #pragma unroll
      for (int q = 0; q < 2; ++q) {
        const float4 v0 = *(const float4*)&tile[rb + dr][wsrc][q * 4];
        const float4 v1 = *(const float4*)&tile[rb + 4 + dr][wsrc][q * 4];
        const float* w8 = wf + q * 8;      // [c0..3][o0..1], broadcast
        const double w0y = (double)w8[0], w0x = (double)w8[1];
        const double w1y = (double)w8[2], w1x = (double)w8[3];
        const double w2y = (double)w8[4], w2x = (double)w8[5];
        const double w3y = (double)w8[6], w3x = (double)w8[7];
        acY[0][q] += (double)v0.x * w0y; acX[0][q] += (double)v0.x * w0x;
        acY[0][q] += (double)v0.y * w1y; acX[0][q] += (double)v0.y * w1x;
        acY[0][q] += (double)v0.z * w2y; acX[0][q] += (double)v0.z * w2x;
        acY[0][q] += (double)v0.w * w3y; acX[0][q] += (double)v0.w * w3x;
        acY[1][q] += (double)v1.x * w0y; acX[1][q] += (double)v1.x * w0x;
        acY[1][q] += (double)v1.y * w1y; acX[1][q] += (double)v1.y * w1x;
        acY[1][q] += (double)v1.z * w2y; acX[1][q] += (double)v1.z * w2x;
        acY[1][q] += (double)v1.w * w3y; acX[1][q] += (double)v1.w * w3x;
      }
    }
  }
  // fp64 index path (matches np float64 reference semantics)
  {
    const double b0 = (double)b_off[0], b1 = (double)b_off[1];
    #pragma unroll
    for (int pi = 0; pi < 2; ++pi) {
      const int r = rb + pi * 4;
      const int h = h0 + r;
      const double sy = acY[pi][0] + acY[pi][1];
      const double sx = acX[pi][0] + acX[pi][1];
      double yd = (double)h + (sy + b0);
      double xd = (double)px_ + (sx + b1);
      yd = yd < 0.0 ? 0.0 : (yd > 127.0 ? 127.0 : yd);
      xd = xd < 0.0 ? 0.0 : (xd > 127.0 ? 127.0 : xd);
      lin_lds[r * 128 + px_] = ((int)yd) * 128 + (int)xd;
    }
  }
  __syncthreads();
  // gather + cast: 1024 px * 256 ch fp32 -> bf16
  const float* imgbase = in + (size_t)b * 16384 * 256;
  unsigned short* obase = samp + ((size_t)(b * 128 + h0)) * 128 * 256;
  #pragma unroll 4
  for (int it = 0; it < 128; ++it) {
    const int idx = it * 512 + t;
    const int p = idx >> 6, cv = idx & 63;
    const float4 v =
        *(const float4*)(imgbase + (size_t)lin_lds[p] * 256 + cv * 4);
    ushort4 o;
    o.x = f2bf(v.x); o.y = f2bf(v.y); o.z = f2bf(v.z); o.w = f2bf(v.w);
    *(ushort4*)(obase + (size_t)p * 256 + cv * 4) = o;
  }
}

// ---------------------------------------------------------------------------
// Kernel 2: w_def (3,3,256,256)[tap][k][n] fp32 -> wT[tap][n][k] bf16
// ---------------------------------------------------------------------------
__global__ __launch_bounds__(256) void k2_wT(const float* __restrict__ wdef,
                                             unsigned short* __restrict__ wT) {
  int g = blockIdx.x * 256 + threadIdx.x;
  int tap = g >> 16;
  int n = (g >> 8) & 255;
  int k = g & 255;
  wT[g] = f2bf(wdef[((size_t)tap * 256 + k) * 256 + n]);
}

// ---------------------------------------------------------------------------
// Kernel 3: implicit-GEMM 3x3 SAME conv, bf16 MFMA.
// (FROZEN from round 9 — 269 µs, MfmaUtil 54.5%)
// ---------------------------------------------------------------------------
struct Frags { bf16x8 a[8]; bf16x8 b[4]; };

__global__ __launch_bounds__(512, 2) void k3_conv(
    const unsigned short* __restrict__ samp, const unsigned short* __restrict__ wT,
    const float* __restrict__ b_def, float* __restrict__ out,
    const unsigned short* __restrict__ zerobuf) {
  __shared__ __align__(16) unsigned char smem[131072];  // A ring 64KB | B ring 64KB

  const int bid0 = blockIdx.x;
  const int mt = (bid0 & 7) * 128 + (bid0 >> 3);
  const int bimg = mt >> 6;
  const int h0 = (mt & 63) * 2;

  const int tid = threadIdx.x;
  const int lane = tid & 63, wave = tid >> 6;
  const int wr = wave >> 2, wc = wave & 3;
  const int r15 = lane & 15, g4 = lane >> 4;
  const int g4eff = g4 ^ ((r15 >> 1) & 3);

  const char* sA = (const char*)smem + (wr * 128 + r15) * 64 + g4eff * 16;
  const char* sB = (const char*)smem + 65536 + (wc * 64 + r15) * 64 + g4eff * 16;

  const int chq = tid & 3;
  const int pix = tid >> 2;
  const int chs = chq ^ ((pix >> 1) & 3);
  const unsigned short* pA[2];
  const unsigned short* pB[2];
  unsigned vmask[2];
  #pragma unroll
  for (int it = 0; it < 2; ++it) {
    const int hh = h0 + it;
    pA[it] = samp + ((size_t)(bimg * 128 + hh) * 128 + pix) * 256 + chs * 8;
    pB[it] = wT + (size_t)(it * 128 + pix) * 256 + chs * 8;
    unsigned m = 0;
    #pragma unroll
    for (int tap = 0; tap < 9; ++tap) {
      const int dr = tap / 3 - 1, dc = tap % 3 - 1;
      if ((unsigned)(hh + dr) < 128u && (unsigned)(pix + dc) < 128u)
        m |= 1u << tap;
    }
    vmask[it] = m;
  }
  const unsigned short* zb = zerobuf + chq * 8;

  f32x4 acc[8][4];
  #pragma unroll
  for (int i = 0; i < 8; ++i)
    #pragma unroll
    for (int j = 0; j < 4; ++j) acc[i][j] = (f32x4){0.f, 0.f, 0.f, 0.f};

  auto stage = [&](int ts, int SLOT) {
    const int tap = ts >> 3, kc = ts & 7;
    const int q = (tap * 11) >> 5;
    const int tapdelta = ((q - 1) * 128 + (tap - q * 3 - 1)) * 256 + kc * 32;
    const int boffg = tap * 65536 + kc * 32;
    unsigned char* Ad = smem + SLOT * 16384;
    unsigned char* Bd = smem + 65536 + SLOT * 16384;
    #pragma unroll
    for (int it = 0; it < 2; ++it)
      gld_lds16(Bd + (it * 512 + tid) * 16, pB[it] + boffg);
    #pragma unroll
    for (int it = 0; it < 2; ++it) {
      const unsigned short* src =
          ((vmask[it] >> tap) & 1) ? (pA[it] + tapdelta) : zb;
      gld_lds16(Ad + (it * 512 + tid) * 16, src);
    }
  };

  auto readfr = [&](Frags& f, int SLOT) {
    #pragma unroll
    for (int ni = 0; ni < 4; ++ni)
      f.b[ni] = *(const bf16x8*)(sB + SLOT * 16384 + ni * 1024);
    #pragma unroll
    for (int mi = 0; mi < 8; ++mi)
      f.a[mi] = *(const bf16x8*)(sA + SLOT * 16384 + mi * 1024);
  };

  auto launder = [&](Frags& f) {
    #pragma unroll
    for (int i = 0; i < 8; ++i) asm volatile("" : "+v"(f.a[i]));
    #pragma unroll
    for (int i = 0; i < 4; ++i) asm volatile("" : "+v"(f.b[i]));
  };

  auto mfma32 = [&](Frags& f) {
    #pragma unroll
    for (int mi = 0; mi < 8; ++mi)
      #pragma unroll
      for (int ni = 0; ni < 4; ++ni)
        acc[mi][ni] = __builtin_amdgcn_mfma_f32_16x16x32_bf16(
            f.a[mi], f.b[ni], acc[mi][ni], 0, 0, 0);
  };

  Frags fr0, fr1;

#define K3_STEP(T_RT, SLOT_NXT, FR_CUR, FR_NXT, DO_READS, DO_STAGE, VMSTR) \
  {                                                                        \
    asm volatile("s_waitcnt lgkmcnt(0)" ::: "memory");                     \
    launder(FR_CUR);                                                       \
    __builtin_amdgcn_sched_barrier(0);                                     \
    __builtin_amdgcn_s_setprio(1);                                         \
    if (DO_READS) readfr(FR_NXT, SLOT_NXT);                                \
    if (DO_STAGE) stage((T_RT) + 3, ((SLOT_NXT) + 2) & 3);                 \
    mfma32(FR_CUR);                                                        \
    if (DO_READS && DO_STAGE) {                                            \
      _Pragma("unroll")                                                    \
      for (int u = 0; u < 4; ++u) {                                        \
        __builtin_amdgcn_sched_group_barrier(0x008, 8, 0);                 \
        __builtin_amdgcn_sched_group_barrier(0x100, 3, 0);                 \
        __builtin_amdgcn_sched_group_barrier(0x030, 1, 0);                 \
      }                                                                    \
    }                                                                      \
    __builtin_amdgcn_s_setprio(0);                                         \
    __builtin_amdgcn_sched_barrier(0);                                     \
    asm volatile("s_waitcnt " VMSTR ::: "memory");                         \
    __builtin_amdgcn_s_barrier();                                          \
    asm volatile("" ::: "memory");                                         \
  }

  stage(0, 0); stage(1, 1); stage(2, 2);
  asm volatile("s_waitcnt vmcnt(4)" ::: "memory");
  __builtin_amdgcn_s_barrier();
  asm volatile("" ::: "memory");
  readfr(fr0, 0);

  for (int tb = 0; tb < 68; tb += 4) {
    K3_STEP(tb + 0, 1, fr0, fr1, true, true, "vmcnt(4)");
    K3_STEP(tb + 1, 2, fr1, fr0, true, true, "vmcnt(4)");
    K3_STEP(tb + 2, 3, fr0, fr1, true, true, "vmcnt(4)");
    K3_STEP(tb + 3, 0, fr1, fr0, true, true, "vmcnt(4)");
  }
  K3_STEP(68, 1, fr0, fr1, true, true,  "vmcnt(4)");
  K3_STEP(69, 2, fr1, fr0, true, false, "vmcnt(0)");
  K3_STEP(70, 3, fr0, fr1, true, false, "vmcnt(0)");
  {
    asm volatile("s_waitcnt lgkmcnt(0)" ::: "memory");
    launder(fr1);
    __builtin_amdgcn_sched_barrier(0);
    mfma32(fr1);
  }
#undef K3_STEP

  const int colg = wc * 64 + r15;
  float bias[4];
  #pragma unroll
  for (int ni = 0; ni < 4; ++ni) bias[ni] = b_def[colg + ni * 16];
  #pragma unroll
  for (int mi = 0; mi < 8; ++mi) {
    const int r0 = wr * 128 + mi * 16 + g4 * 4;
    #pragma unroll
    for (int j = 0; j < 4; ++j) {
      float* orow = out + ((size_t)mt * 256 + r0 + j) * 256 + colg;
      #pragma unroll
      for (int ni = 0; ni < 4; ++ni) orow[ni * 16] = acc[mi][ni][j] + bias[ni];
    }
  }
}

extern "C" void kernel_launch(void* const* d_in, const int* in_sizes, int n_in,
                              void* d_out, int out_size, void* d_ws, size_t ws_size,
                              hipStream_t stream) {
  const float* in = (const float*)d_in[0];     // (16,128,128,256)
  const float* w_off = (const float*)d_in[1];  // (3,3,256,2)
  const float* b_off = (const float*)d_in[2];  // (2,)
  const float* w_def = (const float*)d_in[3];  // (3,3,256,256)
  const float* b_def = (const float*)d_in[4];  // (256,)
  float* out = (float*)d_out;

  char* ws = (char*)d_ws;
  unsigned short* zerobuf = (unsigned short*)ws;                 // 4 KB zeros
  unsigned short* wT = (unsigned short*)(ws + 4096);             // 1,179,648 B
  unsigned short* samp = (unsigned short*)(ws + 4096 + 1179648); // 134,217,728 B

  hipMemsetAsync(ws, 0, 4096, stream);
  hipLaunchKernelGGL(k2_wT, dim3(2304), dim3(256), 0, stream, w_def, wT);
  hipLaunchKernelGGL(k1_offs_gather, dim3(256), dim3(512), 0, stream,
                     in, w_off, b_off, samp);
  hipLaunchKernelGGL(k3_conv, dim3(1024), dim3(512), 0, stream,
                     samp, wT, b_def, out, zerobuf);
}

// Round 15
// 480.096 us; speedup vs baseline: 1.0901x; 1.0901x over previous
//
#include <hip/hip_runtime.h>
#include <hip/hip_bf16.h>

typedef __attribute__((ext_vector_type(8))) short bf16x8;
typedef __attribute__((ext_vector_type(4))) float f32x4;

__device__ __forceinline__ unsigned short f2bf(float f) {
  __hip_bfloat16 h = __float2bfloat16(f);
  return *reinterpret_cast<unsigned short*>(&h);
}

__device__ __forceinline__ void gld_lds16(void* lds, const void* g) {
  __builtin_amdgcn_global_load_lds(
      (const __attribute__((address_space(1))) unsigned int*)g,
      (__attribute__((address_space(3))) unsigned int*)lds, 16, 0, 0);
}

// ---------------------------------------------------------------------------
// Kernel 1 v5 (round-13 proven best, ~205 us, ~94% of its HBM floor):
// 4-row blocks, 512 blocks x 256 threads (2 blocks/CU). Tile reads as
// ds_read_b128 on stride-20 (80B) rows; weights in LDS (wlf) -- v3/v4
// showed s_load weights share lgkmcnt with ds_read and force drains;
// v6 showed 1-block/CU grids expose barrier stalls. This is the optimum
// of the explored k1 space.
// ---------------------------------------------------------------------------
__global__ __launch_bounds__(256) void k1_offs_gather(
    const float* __restrict__ in, const float* __restrict__ w_off,
    const float* __restrict__ b_off, unsigned short* __restrict__ samp) {
  __shared__ float tile[6][128][20];   // 60 KB; 80B row stride
  __shared__ float wlf[288];           // [tap][c(16)][o(2)] current chunk
  __shared__ int lin_lds[512];

  const int bid = blockIdx.x;          // 0..511
  const int b = bid >> 5, h0 = (bid & 31) << 2;
  const int t = threadIdx.x;
  const int px_ = t & 127;
  const int rbase = t >> 7;            // thread owns out rows rbase, rbase+2

  double acY[2][4] = {{0, 0, 0, 0}, {0, 0, 0, 0}};
  double acX[2][4] = {{0, 0, 0, 0}, {0, 0, 0, 0}};

  for (int chunk = 0; chunk < 16; ++chunk) {
    const int c0 = chunk * 16;
    __syncthreads();  // protect tile/wlf from previous chunk's readers
    // weights slice: [tap][c][o], 288 floats -> LDS (broadcast-read later)
    for (int i = t; i < 288; i += 256) {
      const int tap = i >> 5, r = i & 31;
      wlf[i] = w_off[tap * 512 + c0 * 2 + r];
    }
    // stage rows h0-1 .. h0+4, 128 px, 16 ch (3072 float4 = 12/thread)
    #pragma unroll
    for (int it = 0; it < 12; ++it) {
      const int idx = it * 256 + t;          // 0..3071
      const int row = idx >> 9;              // 0..5
      const int rest = idx & 511;
      const int px = rest >> 2, c4 = rest & 3;
      const int hh = h0 - 1 + row;
      float4 v = make_float4(0.f, 0.f, 0.f, 0.f);
      if ((unsigned)hh < 128u)
        v = *(const float4*)(in + ((size_t)(b * 128 + hh) * 128 + px) * 256 +
                             c0 + c4 * 4);
      *(float4*)&tile[row][px][c4 * 4] = v;
    }
    __syncthreads();
    // 9 taps x 4 quads; tile via b128, weights via LDS broadcast
    #pragma unroll
    for (int tap = 0; tap < 9; ++tap) {
      const int dr = tap / 3, dc = tap % 3 - 1;
      const int wsrc = px_ + dc;
      if ((unsigned)wsrc >= 128u) continue;
      const float* wf = &wlf[tap * 32];
      #pragma unroll
      for (int q = 0; q < 4; ++q) {
        const float4 v0 = *(const float4*)&tile[rbase + dr][wsrc][q * 4];
        const float4 v1 = *(const float4*)&tile[rbase + 2 + dr][wsrc][q * 4];
        const float* w8 = wf + q * 8;      // [c0..3][o0..1], broadcast
        const double w0y = (double)w8[0], w0x = (double)w8[1];
        const double w1y = (double)w8[2], w1x = (double)w8[3];
        const double w2y = (double)w8[4], w2x = (double)w8[5];
        const double w3y = (double)w8[6], w3x = (double)w8[7];
        acY[0][q] += (double)v0.x * w0y; acX[0][q] += (double)v0.x * w0x;
        acY[0][q] += (double)v0.y * w1y; acX[0][q] += (double)v0.y * w1x;
        acY[0][q] += (double)v0.z * w2y; acX[0][q] += (double)v0.z * w2x;
        acY[0][q] += (double)v0.w * w3y; acX[0][q] += (double)v0.w * w3x;
        acY[1][q] += (double)v1.x * w0y; acX[1][q] += (double)v1.x * w0x;
        acY[1][q] += (double)v1.y * w1y; acX[1][q] += (double)v1.y * w1x;
        acY[1][q] += (double)v1.z * w2y; acX[1][q] += (double)v1.z * w2x;
        acY[1][q] += (double)v1.w * w3y; acX[1][q] += (double)v1.w * w3x;
      }
    }
  }
  // fp64 index path (matches np float64 reference semantics)
  {
    const double b0 = (double)b_off[0], b1 = (double)b_off[1];
    #pragma unroll
    for (int pi = 0; pi < 2; ++pi) {
      const int r = rbase + pi * 2;
      const int h = h0 + r;
      const double sy =
          (acY[pi][0] + acY[pi][1]) + (acY[pi][2] + acY[pi][3]);
      const double sx =
          (acX[pi][0] + acX[pi][1]) + (acX[pi][2] + acX[pi][3]);
      double yd = (double)h + (sy + b0);
      double xd = (double)px_ + (sx + b1);
      yd = yd < 0.0 ? 0.0 : (yd > 127.0 ? 127.0 : yd);
      xd = xd < 0.0 ? 0.0 : (xd > 127.0 ? 127.0 : xd);
      lin_lds[r * 128 + px_] = ((int)yd) * 128 + (int)xd;
    }
  }
  __syncthreads();
  // gather + cast: 512 px * 256 ch fp32 -> bf16
  const float* imgbase = in + (size_t)b * 16384 * 256;
  unsigned short* obase = samp + ((size_t)(b * 128 + h0)) * 128 * 256;
  #pragma unroll 4
  for (int it = 0; it < 128; ++it) {
    const int idx = it * 256 + t;
    const int p = idx >> 6, cv = idx & 63;
    const float4 v =
        *(const float4*)(imgbase + (size_t)lin_lds[p] * 256 + cv * 4);
    ushort4 o;
    o.x = f2bf(v.x); o.y = f2bf(v.y); o.z = f2bf(v.z); o.w = f2bf(v.w);
    *(ushort4*)(obase + (size_t)p * 256 + cv * 4) = o;
  }
}

// ---------------------------------------------------------------------------
// Kernel 2: w_def (3,3,256,256)[tap][k][n] fp32 -> wT[tap][n][k] bf16
// ---------------------------------------------------------------------------
__global__ __launch_bounds__(256) void k2_wT(const float* __restrict__ wdef,
                                             unsigned short* __restrict__ wT) {
  int g = blockIdx.x * 256 + threadIdx.x;
  int tap = g >> 16;
  int n = (g >> 8) & 255;
  int k = g & 255;
  wT[g] = f2bf(wdef[((size_t)tap * 256 + k) * 256 + n]);
}

// ---------------------------------------------------------------------------
// Kernel 3: implicit-GEMM 3x3 SAME conv, bf16 MFMA.
// (FROZEN from round 9 — 269 µs, MfmaUtil 54.5%)
// ---------------------------------------------------------------------------
struct Frags { bf16x8 a[8]; bf16x8 b[4]; };

__global__ __launch_bounds__(512, 2) void k3_conv(
    const unsigned short* __restrict__ samp, const unsigned short* __restrict__ wT,
    const float* __restrict__ b_def, float* __restrict__ out,
    const unsigned short* __restrict__ zerobuf) {
  __shared__ __align__(16) unsigned char smem[131072];  // A ring 64KB | B ring 64KB

  const int bid0 = blockIdx.x;
  const int mt = (bid0 & 7) * 128 + (bid0 >> 3);
  const int bimg = mt >> 6;
  const int h0 = (mt & 63) * 2;

  const int tid = threadIdx.x;
  const int lane = tid & 63, wave = tid >> 6;
  const int wr = wave >> 2, wc = wave & 3;
  const int r15 = lane & 15, g4 = lane >> 4;
  const int g4eff = g4 ^ ((r15 >> 1) & 3);

  const char* sA = (const char*)smem + (wr * 128 + r15) * 64 + g4eff * 16;
  const char* sB = (const char*)smem + 65536 + (wc * 64 + r15) * 64 + g4eff * 16;

  const int chq = tid & 3;
  const int pix = tid >> 2;
  const int chs = chq ^ ((pix >> 1) & 3);
  const unsigned short* pA[2];
  const unsigned short* pB[2];
  unsigned vmask[2];
  #pragma unroll
  for (int it = 0; it < 2; ++it) {
    const int hh = h0 + it;
    pA[it] = samp + ((size_t)(bimg * 128 + hh) * 128 + pix) * 256 + chs * 8;
    pB[it] = wT + (size_t)(it * 128 + pix) * 256 + chs * 8;
    unsigned m = 0;
    #pragma unroll
    for (int tap = 0; tap < 9; ++tap) {
      const int dr = tap / 3 - 1, dc = tap % 3 - 1;
      if ((unsigned)(hh + dr) < 128u && (unsigned)(pix + dc) < 128u)
        m |= 1u << tap;
    }
    vmask[it] = m;
  }
  const unsigned short* zb = zerobuf + chq * 8;

  f32x4 acc[8][4];
  #pragma unroll
  for (int i = 0; i < 8; ++i)
    #pragma unroll
    for (int j = 0; j < 4; ++j) acc[i][j] = (f32x4){0.f, 0.f, 0.f, 0.f};

  auto stage = [&](int ts, int SLOT) {
    const int tap = ts >> 3, kc = ts & 7;
    const int q = (tap * 11) >> 5;
    const int tapdelta = ((q - 1) * 128 + (tap - q * 3 - 1)) * 256 + kc * 32;
    const int boffg = tap * 65536 + kc * 32;
    unsigned char* Ad = smem + SLOT * 16384;
    unsigned char* Bd = smem + 65536 + SLOT * 16384;
    #pragma unroll
    for (int it = 0; it < 2; ++it)
      gld_lds16(Bd + (it * 512 + tid) * 16, pB[it] + boffg);
    #pragma unroll
    for (int it = 0; it < 2; ++it) {
      const unsigned short* src =
          ((vmask[it] >> tap) & 1) ? (pA[it] + tapdelta) : zb;
      gld_lds16(Ad + (it * 512 + tid) * 16, src);
    }
  };

  auto readfr = [&](Frags& f, int SLOT) {
    #pragma unroll
    for (int ni = 0; ni < 4; ++ni)
      f.b[ni] = *(const bf16x8*)(sB + SLOT * 16384 + ni * 1024);
    #pragma unroll
    for (int mi = 0; mi < 8; ++mi)
      f.a[mi] = *(const bf16x8*)(sA + SLOT * 16384 + mi * 1024);
  };

  auto launder = [&](Frags& f) {
    #pragma unroll
    for (int i = 0; i < 8; ++i) asm volatile("" : "+v"(f.a[i]));
    #pragma unroll
    for (int i = 0; i < 4; ++i) asm volatile("" : "+v"(f.b[i]));
  };

  auto mfma32 = [&](Frags& f) {
    #pragma unroll
    for (int mi = 0; mi < 8; ++mi)
      #pragma unroll
      for (int ni = 0; ni < 4; ++ni)
        acc[mi][ni] = __builtin_amdgcn_mfma_f32_16x16x32_bf16(
            f.a[mi], f.b[ni], acc[mi][ni], 0, 0, 0);
  };

  Frags fr0, fr1;

#define K3_STEP(T_RT, SLOT_NXT, FR_CUR, FR_NXT, DO_READS, DO_STAGE, VMSTR) \
  {                                                                        \
    asm volatile("s_waitcnt lgkmcnt(0)" ::: "memory");                     \
    launder(FR_CUR);                                                       \
    __builtin_amdgcn_sched_barrier(0);                                     \
    __builtin_amdgcn_s_setprio(1);                                         \
    if (DO_READS) readfr(FR_NXT, SLOT_NXT);                                \
    if (DO_STAGE) stage((T_RT) + 3, ((SLOT_NXT) + 2) & 3);                 \
    mfma32(FR_CUR);                                                        \
    if (DO_READS && DO_STAGE) {                                            \
      _Pragma("unroll")                                                    \
      for (int u = 0; u < 4; ++u) {                                        \
        __builtin_amdgcn_sched_group_barrier(0x008, 8, 0);                 \
        __builtin_amdgcn_sched_group_barrier(0x100, 3, 0);                 \
        __builtin_amdgcn_sched_group_barrier(0x030, 1, 0);                 \
      }                                                                    \
    }                                                                      \
    __builtin_amdgcn_s_setprio(0);                                         \
    __builtin_amdgcn_sched_barrier(0);                                     \
    asm volatile("s_waitcnt " VMSTR ::: "memory");                         \
    __builtin_amdgcn_s_barrier();                                          \
    asm volatile("" ::: "memory");                                         \
  }

  stage(0, 0); stage(1, 1); stage(2, 2);
  asm volatile("s_waitcnt vmcnt(4)" ::: "memory");
  __builtin_amdgcn_s_barrier();
  asm volatile("" ::: "memory");
  readfr(fr0, 0);

  for (int tb = 0; tb < 68; tb += 4) {
    K3_STEP(tb + 0, 1, fr0, fr1, true, true, "vmcnt(4)");
    K3_STEP(tb + 1, 2, fr1, fr0, true, true, "vmcnt(4)");
    K3_STEP(tb + 2, 3, fr0, fr1, true, true, "vmcnt(4)");
    K3_STEP(tb + 3, 0, fr1, fr0, true, true, "vmcnt(4)");
  }
  K3_STEP(68, 1, fr0, fr1, true, true,  "vmcnt(4)");
  K3_STEP(69, 2, fr1, fr0, true, false, "vmcnt(0)");
  K3_STEP(70, 3, fr0, fr1, true, false, "vmcnt(0)");
  {
    asm volatile("s_waitcnt lgkmcnt(0)" ::: "memory");
    launder(fr1);
    __builtin_amdgcn_sched_barrier(0);
    mfma32(fr1);
  }
#undef K3_STEP

  const int colg = wc * 64 + r15;
  float bias[4];
  #pragma unroll
  for (int ni = 0; ni < 4; ++ni) bias[ni] = b_def[colg + ni * 16];
  #pragma unroll
  for (int mi = 0; mi < 8; ++mi) {
    const int r0 = wr * 128 + mi * 16 + g4 * 4;
    #pragma unroll
    for (int j = 0; j < 4; ++j) {
      float* orow = out + ((size_t)mt * 256 + r0 + j) * 256 + colg;
      #pragma unroll
      for (int ni = 0; ni < 4; ++ni) orow[ni * 16] = acc[mi][ni][j] + bias[ni];
    }
  }
}

extern "C" void kernel_launch(void* const* d_in, const int* in_sizes, int n_in,
                              void* d_out, int out_size, void* d_ws, size_t ws_size,
                              hipStream_t stream) {
  const float* in = (const float*)d_in[0];     // (16,128,128,256)
  const float* w_off = (const float*)d_in[1];  // (3,3,256,2)
  const float* b_off = (const float*)d_in[2];  // (2,)
  const float* w_def = (const float*)d_in[3];  // (3,3,256,256)
  const float* b_def = (const float*)d_in[4];  // (256,)
  float* out = (float*)d_out;

  char* ws = (char*)d_ws;
  unsigned short* zerobuf = (unsigned short*)ws;                 // 4 KB zeros
  unsigned short* wT = (unsigned short*)(ws + 4096);             // 1,179,648 B
  unsigned short* samp = (unsigned short*)(ws + 4096 + 1179648); // 134,217,728 B

  hipMemsetAsync(ws, 0, 4096, stream);
  hipLaunchKernelGGL(k2_wT, dim3(2304), dim3(256), 0, stream, w_def, wT);
  hipLaunchKernelGGL(k1_offs_gather, dim3(512), dim3(256), 0, stream,
                     in, w_off, b_off, samp);
  hipLaunchKernelGGL(k3_conv, dim3(1024), dim3(512), 0, stream,
                     samp, wT, b_def, out, zerobuf);
}